// Round 7
// baseline (181.559 us; speedup 1.0000x reference)
//
#include <hip/hip_runtime.h>
#include <hip/hip_fp16.h>

#define N    4096
#define SIZE 128
#define CAP  128   // max stored neighbors per row (mean ~21.5), multiple of 4
#define RB   16    // output rows per block (one 16-row MFMA M-tile)
#define TB   1024  // threads per block (fused kernel)
#define SW   256   // degree-sort window (bounds out-store scatter span)

typedef __attribute__((ext_vector_type(8))) _Float16 f16x8;  // MFMA A/B frag (4 VGPRs)
typedef __attribute__((ext_vector_type(2))) __fp16 fp16x2;   // cvt_pkrtz return type
typedef __attribute__((ext_vector_type(4))) float f32x4;     // MFMA C/D frag

__device__ __forceinline__ unsigned int pk2(float lo, float hi) {
    union { fp16x2 v; unsigned int u; } c;
    c.v = __builtin_amdgcn_cvt_pkrtz(lo, hi);   // 1 instr, RTZ
    return c.u;
}
__device__ __forceinline__ __half2 u2h(unsigned int u) {
    union { unsigned int u; __half2 h; } c; c.u = u; return c.h;
}

// ---- kernel A: build row-major padded adjacency index via ballot compaction ----
__global__ __launch_bounds__(256)
void build_csr(const float* __restrict__ nb, int* __restrict__ cnt4,
               int* __restrict__ idx) {
    __shared__ int sc;
    const int j    = blockIdx.x;
    const int lane = threadIdx.x & 63;
    if (threadIdx.x == 0) sc = 0;
    __syncthreads();
    const float4* row4 = (const float4*)(nb + (size_t)j * N);
    int* irow = idx + (size_t)j * CAP;

    float4 v[4];
#pragma unroll
    for (int it = 0; it < 4; ++it) v[it] = row4[threadIdx.x + it * 256];

#pragma unroll
    for (int it = 0; it < 4; ++it) {
        const float e[4] = {v[it].x, v[it].y, v[it].z, v[it].w};
#pragma unroll
        for (int q = 0; q < 4; ++q) {
            const bool nz = (e[q] != 0.0f);
            const unsigned long long m = __ballot(nz);
            if (m != 0ull) {
                int base = 0;
                if (lane == 0) base = atomicAdd(&sc, __popcll(m));
                base = __shfl(base, 0);
                if (nz) {
                    const int p = base + __popcll(m & ((1ull << lane) - 1ull));
                    const int c = 4 * (threadIdx.x + it * 256) + q;
                    if (p < CAP) irow[p] = c;
                }
            }
        }
    }
    __syncthreads();
    if (threadIdx.x == 0) {
        int n  = (sc < CAP) ? sc : CAP;
        int n4 = (n + 3) & ~3;
        for (int p = n; p < n4; ++p) irow[p] = N;  // sentinel -> zero LDS slot
        cnt4[j] = n4 >> 2;
    }
}

// ---- kernel A2: counting-sort each 256-column window by quad-count ----
// perm[w*SW + pos] = column j, ascending c4; ties in arbitrary (atomic) order,
// which is harmless: per-column summation order is fixed by its own list.
__global__ __launch_bounds__(SW)
void sortw(const int* __restrict__ cnt4, int* __restrict__ perm) {
    __shared__ int hist[65];
    __shared__ int ofs[65];
    const int w = blockIdx.x, t = threadIdx.x;
    if (t < 65) hist[t] = 0;
    __syncthreads();
    const int j = w * SW + t;
    int k = cnt4[j]; if (k > 64) k = 64;
    atomicAdd(&hist[k], 1);
    __syncthreads();
    if (t == 0) {
        int s = 0;
        for (int b = 0; b <= 64; ++b) { ofs[b] = s; s += hist[b]; }
    }
    __syncthreads();
    const int pos = atomicAdd(&ofs[k], 1);
    perm[w * SW + pos] = j;
}

// ---- kernel B: swizzle f into f16 MFMA fragment order, LDS-staged ----
// A[(tile*4+ks)*64+lane][jj] = f16(wq[k]wk[k]f[k][tile*16+col]), B without scale;
// k = ks*32 + (lane>>4)*8 + jj, col = lane&15 (layout verified round 4).
__global__ __launch_bounds__(256)
void prep(const float* __restrict__ f, const float* __restrict__ wq,
          const float* __restrict__ wk, _Float16* __restrict__ Af,
          _Float16* __restrict__ Bf) {
    __shared__ float sf[SIZE][16];
    __shared__ float sqw[SIZE];
    const int t    = threadIdx.x;
    const int tile = blockIdx.x;
    if (t < SIZE) sqw[t] = wq[t] * wk[t];
    const int col0 = t & 15;
#pragma unroll
    for (int it = 0; it < 8; ++it) {
        const int k = (t >> 4) + it * 16;
        sf[k][col0] = f[(size_t)k * N + tile * 16 + col0];
    }
    __syncthreads();

    const int ks   = t >> 6;
    const int lane = t & 63;
    const int quad = lane >> 4;
    const int col  = lane & 15;
    f16x8 va, vb;
#pragma unroll
    for (int jj = 0; jj < 8; ++jj) {
        const int k = ks * 32 + quad * 8 + jj;
        const float v = sf[k][col];
        va[jj] = (_Float16)(sqw[k] * v);
        vb[jj] = (_Float16)v;
    }
    const size_t o = (size_t)(tile * 4 + ks) * 64 + lane;
    ((f16x8*)Af)[o] = va;
    ((f16x8*)Bf)[o] = vb;
}

// ---- fused kernel: 16 output rows per block via f16 MFMA + packed-f16 gather ----
__global__ __launch_bounds__(TB, 4)
void fused(const _Float16* __restrict__ Af, const _Float16* __restrict__ Bf,
           const int* __restrict__ cnt4, const int* __restrict__ idx,
           const int* __restrict__ perm, float* __restrict__ out) {
    // sA: rows 0-7 (8 f16/column), sB: rows 8-15, offset +2 slots; +1 zero sentinel.
    __shared__ uint4 Sb[2 * N + 3];           // 131,120 B
    uint4* const sA = Sb;
    uint4* const sB = Sb + N + 2;
    const int t    = threadIdx.x;
    const int lane = t & 63;
    const int wv   = t >> 6;
    const int quad = lane >> 4;
    const int i0   = blockIdx.x * RB;

    // ---- phase 1 ----
    f16x8 af[4];
    const f16x8* Ap = (const f16x8*)Af + (size_t)blockIdx.x * 4 * 64;
#pragma unroll
    for (int ks = 0; ks < 4; ++ks) af[ks] = Ap[ks * 64 + lane];
    const f16x8* Bp = (const f16x8*)Bf;

#pragma unroll 4
    for (int ti = 0; ti < 16; ++ti) {
        const int nt = wv * 16 + ti;          // column tile: j = nt*16 .. nt*16+15
        f32x4 acc = {0.f, 0.f, 0.f, 0.f};
#pragma unroll
        for (int ks = 0; ks < 4; ++ks) {
            const f16x8 bfrag = Bp[(size_t)(nt * 4 + ks) * 64 + lane];
            acc = __builtin_amdgcn_mfma_f32_16x16x32_f16(af[ks], bfrag, acc, 0, 0, 0);
        }
        // C/D: col = lane&15, row = quad*4 + reg
        const int j = nt * 16 + (lane & 15);
        uint2 p;
        p.x = pk2(__expf(acc[0]), __expf(acc[1]));
        p.y = pk2(__expf(acc[2]), __expf(acc[3]));
        uint2* base = (quad < 2) ? (uint2*)&sA[j] : (uint2*)&sB[j];
        base[quad & 1] = p;
    }
    if (t == 0) {
        sA[N] = make_uint4(0u, 0u, 0u, 0u);
        sB[N] = make_uint4(0u, 0u, 0u, 0u);
    }
    __syncthreads();

    // ---- phase 2: degree-balanced sparse gather, packed-f16 accumulation ----
    for (int u = 0; u < N / TB; ++u) {
        const int jp = perm[t + u * TB];      // wave's 64 columns have ~equal degree
        const int c4 = cnt4[jp];
        const int4* irow = (const int4*)(idx + (size_t)jp * CAP);
        __half2 d0[8], d1[8];                 // two independent sets (chain halved)
        const __half2 z = u2h(0u);
#pragma unroll
        for (int r = 0; r < 8; ++r) { d0[r] = z; d1[r] = z; }

        int4 k = irow[0];
        for (int c = 0; c < c4; ++c) {
            const int4 kn = (c + 1 < c4) ? irow[c + 1] : k;
            const uint4 ax = sA[k.x], bx = sB[k.x];
            const uint4 ay = sA[k.y], by = sB[k.y];
            const uint4 az = sA[k.z], bz = sB[k.z];
            const uint4 aw = sA[k.w], bw = sB[k.w];
            d0[0] = __hadd2(d0[0], u2h(ax.x)); d1[0] = __hadd2(d1[0], u2h(ay.x));
            d0[1] = __hadd2(d0[1], u2h(ax.y)); d1[1] = __hadd2(d1[1], u2h(ay.y));
            d0[2] = __hadd2(d0[2], u2h(ax.z)); d1[2] = __hadd2(d1[2], u2h(ay.z));
            d0[3] = __hadd2(d0[3], u2h(ax.w)); d1[3] = __hadd2(d1[3], u2h(ay.w));
            d0[4] = __hadd2(d0[4], u2h(bx.x)); d1[4] = __hadd2(d1[4], u2h(by.x));
            d0[5] = __hadd2(d0[5], u2h(bx.y)); d1[5] = __hadd2(d1[5], u2h(by.y));
            d0[6] = __hadd2(d0[6], u2h(bx.z)); d1[6] = __hadd2(d1[6], u2h(by.z));
            d0[7] = __hadd2(d0[7], u2h(bx.w)); d1[7] = __hadd2(d1[7], u2h(by.w));
            d0[0] = __hadd2(d0[0], u2h(az.x)); d1[0] = __hadd2(d1[0], u2h(aw.x));
            d0[1] = __hadd2(d0[1], u2h(az.y)); d1[1] = __hadd2(d1[1], u2h(aw.y));
            d0[2] = __hadd2(d0[2], u2h(az.z)); d1[2] = __hadd2(d1[2], u2h(aw.z));
            d0[3] = __hadd2(d0[3], u2h(az.w)); d1[3] = __hadd2(d1[3], u2h(aw.w));
            d0[4] = __hadd2(d0[4], u2h(bz.x)); d1[4] = __hadd2(d1[4], u2h(bw.x));
            d0[5] = __hadd2(d0[5], u2h(bz.y)); d1[5] = __hadd2(d1[5], u2h(bw.y));
            d0[6] = __hadd2(d0[6], u2h(bz.z)); d1[6] = __hadd2(d1[6], u2h(bw.z));
            d0[7] = __hadd2(d0[7], u2h(bz.w)); d1[7] = __hadd2(d1[7], u2h(bw.w));
            k = kn;
        }
        const uint4 na = sA[jp], nb2 = sB[jp];
        const unsigned int nu[8] = {na.x, na.y, na.z, na.w, nb2.x, nb2.y, nb2.z, nb2.w};
#pragma unroll
        for (int i = 0; i < 8; ++i) {
            const __half2 dd = __hadd2(d0[i], d1[i]);
            const __half2 nn = u2h(nu[i]);
            out[(size_t)(i0 + 2 * i + 0) * N + jp] =
                __low2float(nn)  * __builtin_amdgcn_rcpf(__low2float(dd));
            out[(size_t)(i0 + 2 * i + 1) * N + jp] =
                __high2float(nn) * __builtin_amdgcn_rcpf(__high2float(dd));
        }
    }
}

extern "C" void kernel_launch(void* const* d_in, const int* in_sizes, int n_in,
                              void* d_out, int out_size, void* d_ws, size_t ws_size,
                              hipStream_t stream) {
    const float* f  = (const float*)d_in[0];   // [SIZE, N]
    const float* nb = (const float*)d_in[1];   // [N, N]
    const float* wq = (const float*)d_in[2];   // [SIZE]
    const float* wk = (const float*)d_in[3];   // [SIZE]
    float* out = (float*)d_out;                // [N, N]

    // workspace: cnt4 (N) | idx (N*CAP) | perm (N) | Af (512K f16) | Bf (512K f16) ~= 4.2 MB
    int*      cnt4 = (int*)d_ws;
    int*      idx  = cnt4 + N;
    int*      perm = idx + (size_t)N * CAP;
    _Float16* Af   = (_Float16*)(perm + N);
    _Float16* Bf   = Af + (size_t)256 * 4 * 64 * 8;

    build_csr<<<N, 256, 0, stream>>>(nb, cnt4, idx);
    sortw<<<N / SW, SW, 0, stream>>>(cnt4, perm);
    prep<<<256, 256, 0, stream>>>(f, wq, wk, Af, Bf);
    fused<<<N / RB, TB, 0, stream>>>(Af, Bf, cnt4, idx, perm, out);
}

// Round 8
// 177.085 us; speedup vs baseline: 1.0253x; 1.0253x over previous
//
#include <hip/hip_runtime.h>
#include <hip/hip_fp16.h>

#define N    4096
#define SIZE 128
#define CAP  128   // max stored neighbors per row (mean ~21.5)
#define RB   16    // output rows per block (one 16-row MFMA M-tile)
#define TB   1024  // threads per block (fused kernel)
#define SW   256   // degree-sort window (must divide TB)

typedef __attribute__((ext_vector_type(8))) _Float16 f16x8;  // MFMA A/B frag (4 VGPRs)
typedef __attribute__((ext_vector_type(2))) __fp16 fp16x2;   // cvt_pkrtz return type
typedef __attribute__((ext_vector_type(4))) float f32x4;     // MFMA C/D frag

__device__ __forceinline__ unsigned int pk2(float lo, float hi) {
    union { fp16x2 v; unsigned int u; } c;
    c.v = __builtin_amdgcn_cvt_pkrtz(lo, hi);   // 1 instr, RTZ
    return c.u;
}
__device__ __forceinline__ __half2 u2h(unsigned int u) {
    union { unsigned int u; __half2 h; } c; c.u = u; return c.h;
}

// ---- kernel A: build row-major adjacency index via ballot compaction ----
// idx[j*CAP + c] = c-th nonzero column of row j; cnt[j] = real count (no padding).
__global__ __launch_bounds__(256)
void build_csr(const float* __restrict__ nb, int* __restrict__ cnt,
               int* __restrict__ idx) {
    __shared__ int sc;
    const int j    = blockIdx.x;
    const int lane = threadIdx.x & 63;
    if (threadIdx.x == 0) sc = 0;
    __syncthreads();
    const float4* row4 = (const float4*)(nb + (size_t)j * N);
    int* irow = idx + (size_t)j * CAP;

    float4 v[4];
#pragma unroll
    for (int it = 0; it < 4; ++it) v[it] = row4[threadIdx.x + it * 256];

#pragma unroll
    for (int it = 0; it < 4; ++it) {
        const float e[4] = {v[it].x, v[it].y, v[it].z, v[it].w};
#pragma unroll
        for (int q = 0; q < 4; ++q) {
            const bool nz = (e[q] != 0.0f);
            const unsigned long long m = __ballot(nz);
            if (m != 0ull) {
                int base = 0;
                if (lane == 0) base = atomicAdd(&sc, __popcll(m));
                base = __shfl(base, 0);
                if (nz) {
                    const int p = base + __popcll(m & ((1ull << lane) - 1ull));
                    const int c = 4 * (threadIdx.x + it * 256) + q;
                    if (p < CAP) irow[p] = c;
                }
            }
        }
    }
    __syncthreads();
    if (threadIdx.x == 0) cnt[j] = (sc < CAP) ? sc : CAP;
}

// ---- kernel A2: counting-sort each 256-column window by degree ----
// perm[w*SW + pos] = column j, ascending cnt; any tie order is correct
// (each column's own summation order is unchanged).
__global__ __launch_bounds__(SW)
void sortw(const int* __restrict__ cnt, int* __restrict__ perm) {
    __shared__ int hist[128];
    __shared__ int ofs[128];
    const int w = blockIdx.x, t = threadIdx.x;
    if (t < 128) hist[t] = 0;
    __syncthreads();
    const int j = w * SW + t;
    int k = cnt[j]; if (k > 127) k = 127;
    atomicAdd(&hist[k], 1);
    __syncthreads();
    if (t == 0) {
        int s = 0;
        for (int b = 0; b < 128; ++b) { ofs[b] = s; s += hist[b]; }
    }
    __syncthreads();
    const int pos = atomicAdd(&ofs[k], 1);
    perm[w * SW + pos] = j;
}

// ---- kernel B: swizzle f into f16 MFMA fragment order, LDS-staged ----
// A[(tile*4+ks)*64+lane][jj] = f16(wq[k]wk[k]f[k][tile*16+col]), B without scale;
// k = ks*32 + (lane>>4)*8 + jj, col = lane&15 (layout verified round 4).
__global__ __launch_bounds__(256)
void prep(const float* __restrict__ f, const float* __restrict__ wq,
          const float* __restrict__ wk, _Float16* __restrict__ Af,
          _Float16* __restrict__ Bf) {
    __shared__ float sf[SIZE][16];
    __shared__ float sqw[SIZE];
    const int t    = threadIdx.x;
    const int tile = blockIdx.x;
    if (t < SIZE) sqw[t] = wq[t] * wk[t];
    const int col0 = t & 15;
#pragma unroll
    for (int it = 0; it < 8; ++it) {
        const int k = (t >> 4) + it * 16;
        sf[k][col0] = f[(size_t)k * N + tile * 16 + col0];
    }
    __syncthreads();

    const int ks   = t >> 6;
    const int lane = t & 63;
    const int quad = lane >> 4;
    const int col  = lane & 15;
    f16x8 va, vb;
#pragma unroll
    for (int jj = 0; jj < 8; ++jj) {
        const int k = ks * 32 + quad * 8 + jj;
        const float v = sf[k][col];
        va[jj] = (_Float16)(sqw[k] * v);
        vb[jj] = (_Float16)v;
    }
    const size_t o = (size_t)(tile * 4 + ks) * 64 + lane;
    ((f16x8*)Af)[o] = va;
    ((f16x8*)Bf)[o] = vb;
}

// ---- fused kernel: 16 output rows per block; MFMA phase 1, degree-balanced
// gather with LDS-staged coalesced stores in phase 2 ----
__global__ __launch_bounds__(TB, 1)
void fused(const _Float16* __restrict__ Af, const _Float16* __restrict__ Bf,
           const int* __restrict__ cnt, const int* __restrict__ idx,
           const int* __restrict__ perm, float* __restrict__ out) {
    __shared__ uint4 Sb[2 * N];          // 131,072 B: sA = [0,N), sB = [N,2N)
    __shared__ unsigned int stg[8][TB];  //  32,768 B: f16-pair output stage
    uint4* const sA = Sb;
    uint4* const sB = Sb + N;
    const int t    = threadIdx.x;
    const int lane = t & 63;
    const int wv   = t >> 6;
    const int quad = lane >> 4;
    const int i0   = blockIdx.x * RB;

    // ---- phase 1 ----
    f16x8 af[4];
    const f16x8* Ap = (const f16x8*)Af + (size_t)blockIdx.x * 4 * 64;
#pragma unroll
    for (int ks = 0; ks < 4; ++ks) af[ks] = Ap[ks * 64 + lane];
    const f16x8* Bp = (const f16x8*)Bf;

#pragma unroll 4
    for (int ti = 0; ti < 16; ++ti) {
        const int nt = wv * 16 + ti;          // column tile: j = nt*16 .. nt*16+15
        f32x4 acc = {0.f, 0.f, 0.f, 0.f};
#pragma unroll
        for (int ks = 0; ks < 4; ++ks) {
            const f16x8 bfrag = Bp[(size_t)(nt * 4 + ks) * 64 + lane];
            acc = __builtin_amdgcn_mfma_f32_16x16x32_f16(af[ks], bfrag, acc, 0, 0, 0);
        }
        // C/D: col = lane&15, row = quad*4 + reg
        const int j = nt * 16 + (lane & 15);
        uint2 p;
        p.x = pk2(__expf(acc[0]), __expf(acc[1]));
        p.y = pk2(__expf(acc[2]), __expf(acc[3]));
        uint2* base = (quad < 2) ? (uint2*)&sA[j] : (uint2*)&sB[j];
        base[quad & 1] = p;
    }
    __syncthreads();

    // ---- phase 2 ----
    for (int u = 0; u < N / TB; ++u) {
        const int jp = perm[t + u * TB];      // wave's 64 columns have ~equal degree
        const int n  = cnt[jp];
        const int c4 = n >> 2;
        const int* irow = idx + (size_t)jp * CAP;
        const int4* irow4 = (const int4*)irow;
        __half2 d0[8], d1[8];                 // two independent sets (chain halved)
        const __half2 z = u2h(0u);
#pragma unroll
        for (int r = 0; r < 8; ++r) { d0[r] = z; d1[r] = z; }

        if (c4 > 0) {
            int4 k = irow4[0];
            for (int c = 0; c < c4; ++c) {
                const int4 kn = (c + 1 < c4) ? irow4[c + 1] : k;
                const uint4 ax = sA[k.x], bx = sB[k.x];
                const uint4 ay = sA[k.y], by = sB[k.y];
                const uint4 az = sA[k.z], bz = sB[k.z];
                const uint4 aw = sA[k.w], bw = sB[k.w];
                d0[0] = __hadd2(d0[0], u2h(ax.x)); d1[0] = __hadd2(d1[0], u2h(ay.x));
                d0[1] = __hadd2(d0[1], u2h(ax.y)); d1[1] = __hadd2(d1[1], u2h(ay.y));
                d0[2] = __hadd2(d0[2], u2h(ax.z)); d1[2] = __hadd2(d1[2], u2h(ay.z));
                d0[3] = __hadd2(d0[3], u2h(ax.w)); d1[3] = __hadd2(d1[3], u2h(ay.w));
                d0[4] = __hadd2(d0[4], u2h(bx.x)); d1[4] = __hadd2(d1[4], u2h(by.x));
                d0[5] = __hadd2(d0[5], u2h(bx.y)); d1[5] = __hadd2(d1[5], u2h(by.y));
                d0[6] = __hadd2(d0[6], u2h(bx.z)); d1[6] = __hadd2(d1[6], u2h(by.z));
                d0[7] = __hadd2(d0[7], u2h(bx.w)); d1[7] = __hadd2(d1[7], u2h(by.w));
                d0[0] = __hadd2(d0[0], u2h(az.x)); d1[0] = __hadd2(d1[0], u2h(aw.x));
                d0[1] = __hadd2(d0[1], u2h(az.y)); d1[1] = __hadd2(d1[1], u2h(aw.y));
                d0[2] = __hadd2(d0[2], u2h(az.z)); d1[2] = __hadd2(d1[2], u2h(aw.z));
                d0[3] = __hadd2(d0[3], u2h(az.w)); d1[3] = __hadd2(d1[3], u2h(aw.w));
                d0[4] = __hadd2(d0[4], u2h(bz.x)); d1[4] = __hadd2(d1[4], u2h(bw.x));
                d0[5] = __hadd2(d0[5], u2h(bz.y)); d1[5] = __hadd2(d1[5], u2h(bw.y));
                d0[6] = __hadd2(d0[6], u2h(bz.z)); d1[6] = __hadd2(d1[6], u2h(bw.z));
                d0[7] = __hadd2(d0[7], u2h(bz.w)); d1[7] = __hadd2(d1[7], u2h(bw.w));
                k = kn;
            }
        }
        for (int m = 4 * c4; m < n; ++m) {    // scalar tail, <=3 iters
            const int kk = irow[m];
            const uint4 a = sA[kk], b = sB[kk];
            d0[0] = __hadd2(d0[0], u2h(a.x)); d0[1] = __hadd2(d0[1], u2h(a.y));
            d0[2] = __hadd2(d0[2], u2h(a.z)); d0[3] = __hadd2(d0[3], u2h(a.w));
            d0[4] = __hadd2(d0[4], u2h(b.x)); d0[5] = __hadd2(d0[5], u2h(b.y));
            d0[6] = __hadd2(d0[6], u2h(b.z)); d0[7] = __hadd2(d0[7], u2h(b.w));
        }

        const uint4 na = sA[jp], nb2 = sB[jp];
        const unsigned int nu[8] = {na.x, na.y, na.z, na.w, nb2.x, nb2.y, nb2.z, nb2.w};
        const int jl = jp & (TB - 1);         // perm windows align with u-chunks
#pragma unroll
        for (int i = 0; i < 8; ++i) {
            const __half2 dd = __hadd2(d0[i], d1[i]);
            const __half2 nn = u2h(nu[i]);
            const float lo = __low2float(nn)  * __builtin_amdgcn_rcpf(__low2float(dd));
            const float hi = __high2float(nn) * __builtin_amdgcn_rcpf(__high2float(dd));
            stg[i][jl] = pk2(lo, hi);         // scattered b32, ~2-way conflicts (free)
        }
        __syncthreads();
        const int j = t + u * TB;             // coalesced store column
#pragma unroll
        for (int i = 0; i < 8; ++i) {
            const __half2 o2 = u2h(stg[i][t]);  // conflict-free b32
            out[(size_t)(i0 + 2 * i + 0) * N + j] = __low2float(o2);
            out[(size_t)(i0 + 2 * i + 1) * N + j] = __high2float(o2);
        }
        __syncthreads();                      // protect stg before next u
    }
}

extern "C" void kernel_launch(void* const* d_in, const int* in_sizes, int n_in,
                              void* d_out, int out_size, void* d_ws, size_t ws_size,
                              hipStream_t stream) {
    const float* f  = (const float*)d_in[0];   // [SIZE, N]
    const float* nb = (const float*)d_in[1];   // [N, N]
    const float* wq = (const float*)d_in[2];   // [SIZE]
    const float* wk = (const float*)d_in[3];   // [SIZE]
    float* out = (float*)d_out;                // [N, N]

    // workspace: cnt (N) | idx (N*CAP) | perm (N) | Af (512K f16) | Bf (512K f16) ~= 4.2 MB
    int*      cnt  = (int*)d_ws;
    int*      idx  = cnt + N;
    int*      perm = idx + (size_t)N * CAP;
    _Float16* Af   = (_Float16*)(perm + N);
    _Float16* Bf   = Af + (size_t)256 * 4 * 64 * 8;

    build_csr<<<N, 256, 0, stream>>>(nb, cnt, idx);
    sortw<<<N / SW, SW, 0, stream>>>(cnt, perm);
    prep<<<256, 256, 0, stream>>>(f, wq, wk, Af, Bf);
    fused<<<N / RB, TB, 0, stream>>>(Af, Bf, cnt, idx, perm, out);
}